// Round 6
// baseline (864.437 us; speedup 1.0000x reference)
//
#include <hip/hip_runtime.h>

// CRF log-likelihood. B=256, L=1024, D=126, T=128. 128 blocks x 512 thr,
// TWO batches per THREAD (R9). R5 lesson: step = 966cyc of which only
// ~300 is VALU issue; the ~650 remainder is serial chain + barrier stall
// shared by both lockstep waves/SIMD (deleting half the LDS work changed
// nothing). R2 lesson: a second batch in OTHER waves aligns stalls
// (lockstep barrier) and fails. Fix: second batch IN-LANE -- each thread
// runs two independent recursions; their FMA/reduce chains interleave and
// fill the stall window, and one barrier now advances two batch-steps.
// treg (transition weights) is batch-independent: shared, zero extra regs.
// Per-batch structure unchanged from R5: 4 outputs x 8 inputs per thread,
// sig-permuted E, DPP row_ror ring reduce, rebase every 4th step, logits
// prefetched global->reg 4 steps ahead, raw lgkmcnt(0)+s_barrier.

typedef float v2f __attribute__((ext_vector_type(2)));

#define NEGV  (-10000.0f)
#define LOG2E 1.4426950408889634f
#define LN2   0.6931471805599453f

constexpr int Bc = 256, Lc = 1024, Dc = 126, Tc = 128;

#if __has_builtin(__builtin_amdgcn_exp2f)
#define FEXP2(x) __builtin_amdgcn_exp2f(x)
#else
#define FEXP2(x) exp2f(x)
#endif
#if __has_builtin(__builtin_amdgcn_logf)
#define FLOG2(x) __builtin_amdgcn_logf(x)
#else
#define FLOG2(x) log2f(x)
#endif

#if __has_builtin(__builtin_amdgcn_mov_dpp)
#define DPPF(x, ctrl) __int_as_float(__builtin_amdgcn_mov_dpp(__float_as_int(x), (ctrl), 0xF, 0xF, true))
#define ROR1(x) DPPF(x, 0x121)
#define ROR2(x) DPPF(x, 0x122)
#define ROR4(x) DPPF(x, 0x124)
#define ROR8(x) DPPF(x, 0x128)
#else
#define ROR1(x) __shfl_xor((x), 1, 64)
#define ROR2(x) __shfl_xor((x), 2, 64)
#define ROR4(x) __shfl_xor((x), 4, 64)
#define ROR8(x) __shfl_xor((x), 8, 64)
#endif

#define STEP_BARRIER() asm volatile("s_waitcnt lgkmcnt(0)\n\ts_barrier" ::: "memory")

__device__ __forceinline__ int SIG(int q) { return q ^ (q >> 3); }   // bijective on [0,32)
__device__ __forceinline__ int Fmap(int k) { return 4 * SIG(k >> 2) + (k & 3); }

__global__ __launch_bounds__(512, 1) void crf_fwd_kernel(
    const float* __restrict__ x,      // [B, L, D]
    const float* __restrict__ trans,  // [T, T] row-major
    const int*   __restrict__ x_len,  // [B]
    const int*   __restrict__ tag,    // [B, L]
    float*       __restrict__ out)    // [B]
{
    __shared__ __align__(16) float EL[2][2][Tc];   // [batch][dbuf][state], sig-permuted
    __shared__ float red[2][12];                   // per-batch epilogue reductions

    const int bb  = blockIdx.x << 1;
    const int tid = threadIdx.x;
    const int w   = tid >> 6;             // wave 0..7
    const int l6  = tid & 63;
    const int o   = l6 & 15;              // k-octet: k in [8o, 8o+8)
    const int jg  = (w << 2) | (l6 >> 4); // j-group 0..31: j in [4jg, 4jg+4)
    const int len0 = x_len[bb];
    const int len1 = x_len[bb + 1];
    const int lenmax = (len0 > len1) ? len0 : len1;

    const float* xb0 = x + (size_t)bb * Lc * Dc;
    const float* xb1 = xb0 + (size_t)Lc * Dc;
    const int*   tb0 = tag + (size_t)bb * Lc;
    const int*   tb1 = tb0 + Lc;

    const int  f0 = 4 * SIG(2 * o);       // E read: k = 8o..8o+3
    const int  f1 = 4 * SIG(2 * o + 1);   //         k = 8o+4..8o+7
    const int  wq = 4 * SIG(jg);          // E write: quad jg (b128)
    const bool hiBad = (jg == 31);        // j=126,127 are the NEG pad

    // ---- constant weights: treg[g][c] = exp(trans[4jg+g, 8o+c]) (shared) ----
    float treg[4][8];
#pragma unroll
    for (int g = 0; g < 4; ++g) {
        const float4* tp = reinterpret_cast<const float4*>(trans + (4*jg + g) * Tc + 8*o);
        float4 t0 = tp[0], t1 = tp[1];
        treg[g][0] = FEXP2(t0.x * LOG2E); treg[g][1] = FEXP2(t0.y * LOG2E);
        treg[g][2] = FEXP2(t0.z * LOG2E); treg[g][3] = FEXP2(t0.w * LOG2E);
        treg[g][4] = FEXP2(t1.x * LOG2E); treg[g][5] = FEXP2(t1.y * LOG2E);
        treg[g][6] = FEXP2(t1.z * LOG2E); treg[g][7] = FEXP2(t1.w * LOG2E);
    }

    // ---- init E = delta(START=126), both batches ----
    if (tid < Tc) {
        float v = (tid == Tc - 2) ? 1.0f : 0.0f;
        EL[0][0][Fmap(tid)] = v;
        EL[1][0][Fmap(tid)] = v;
    }
    __syncthreads();

    // logits of row LS (clamped), j = 4jg..4jg+3, batch Q
#define LOADP(Q, LS, A, B2) {                                           \
        int _s = (LS); const int _lm = len##Q - 1; if (_s > _lm) _s = _lm; \
        const float* _r = xb##Q + (size_t)_s * Dc + 4 * jg;             \
        A  = *reinterpret_cast<const v2f*>(_r);                         \
        B2 = hiBad ? (v2f){NEGV, NEGV}                                  \
                   : *reinterpret_cast<const v2f*>(_r + 2); }

    v2f Pa0, Pb0, Pa1, Pb1;               // emission factors, current step
    {
        v2f a, b2;
        LOADP(0, 0, a, b2);
        Pa0 = (v2f){FEXP2(a.x * LOG2E),  FEXP2(a.y * LOG2E)};
        Pb0 = (v2f){FEXP2(b2.x * LOG2E), FEXP2(b2.y * LOG2E)};
        LOADP(1, 0, a, b2);
        Pa1 = (v2f){FEXP2(a.x * LOG2E),  FEXP2(a.y * LOG2E)};
        Pb1 = (v2f){FEXP2(b2.x * LOG2E), FEXP2(b2.y * LOG2E)};
    }
    // 4-deep prefetch ring, statically indexed (rule #20)
    v2f s0A0,s0B0,s0A1,s0B1, s1A0,s1B0,s1A1,s1B1,
        s2A0,s2B0,s2A1,s2B1, s3A0,s3B0,s3A1,s3B1;
    LOADP(0, 1, s1A0, s1B0); LOADP(1, 1, s1A1, s1B1);
    LOADP(0, 2, s2A0, s2B0); LOADP(1, 2, s2A1, s2B1);
    LOADP(0, 3, s3A0, s3B0); LOADP(1, 3, s3A1, s3B1);
    s0A0 = s1A0; s0B0 = s1B0; s0A1 = s1A1; s0B1 = s1B1;   // refilled at C=0

    int Mint0 = 0, Mint1 = 0;             // exact base-2 shift accumulators
    const int len4 = (lenmax + 3) & ~3;

#define MV32(ea, eb, S0, S1, S2, S3)                                                      \
    S0 = treg[0][0]*ea.x; S1 = treg[1][0]*ea.x; S2 = treg[2][0]*ea.x; S3 = treg[3][0]*ea.x; \
    S0=fmaf(treg[0][1],ea.y,S0); S1=fmaf(treg[1][1],ea.y,S1); S2=fmaf(treg[2][1],ea.y,S2); S3=fmaf(treg[3][1],ea.y,S3); \
    S0=fmaf(treg[0][2],ea.z,S0); S1=fmaf(treg[1][2],ea.z,S1); S2=fmaf(treg[2][2],ea.z,S2); S3=fmaf(treg[3][2],ea.z,S3); \
    S0=fmaf(treg[0][3],ea.w,S0); S1=fmaf(treg[1][3],ea.w,S1); S2=fmaf(treg[2][3],ea.w,S2); S3=fmaf(treg[3][3],ea.w,S3); \
    S0=fmaf(treg[0][4],eb.x,S0); S1=fmaf(treg[1][4],eb.x,S1); S2=fmaf(treg[2][4],eb.x,S2); S3=fmaf(treg[3][4],eb.x,S3); \
    S0=fmaf(treg[0][5],eb.y,S0); S1=fmaf(treg[1][5],eb.y,S1); S2=fmaf(treg[2][5],eb.y,S2); S3=fmaf(treg[3][5],eb.y,S3); \
    S0=fmaf(treg[0][6],eb.z,S0); S1=fmaf(treg[1][6],eb.z,S1); S2=fmaf(treg[2][6],eb.z,S2); S3=fmaf(treg[3][6],eb.z,S3); \
    S0=fmaf(treg[0][7],eb.w,S0); S1=fmaf(treg[1][7],eb.w,S1); S2=fmaf(treg[2][7],eb.w,S2); S3=fmaf(treg[3][7],eb.w,S3);

#define RINGADD(S0, S1, S2, S3)                                     \
    S0 += ROR1(S0); S1 += ROR1(S1); S2 += ROR1(S2); S3 += ROR1(S3); \
    S0 += ROR2(S0); S1 += ROR2(S1); S2 += ROR2(S2); S3 += ROR2(S3); \
    S0 += ROR4(S0); S1 += ROR4(S1); S2 += ROR4(S2); S3 += ROR4(S3); \
    S0 += ROR8(S0); S1 += ROR8(S1); S2 += ROR8(S2); S3 += ROR8(S3);

#define RINGMAX(M)                                                  \
    M = fmaxf(M, ROR1(M)); M = fmaxf(M, ROR2(M));                   \
    M = fmaxf(M, ROR4(M)); M = fmaxf(M, ROR8(M));

    // ---- forward recursion: one raw barrier advances BOTH batches ----
#define BODY(C, L0A, L0B, N0A, N0B, L1A, L1B, N1A, N1B) {                       \
        const int  l    = l4 + (C);                                             \
        const bool act0 = l < len0, act1 = l < len1;  /* block-uniform */       \
        const int  p    = (C) & 1;                                              \
        LOADP(0, l + 4, L0A, L0B);        /* refill slot C, used at C+3 */      \
        LOADP(1, l + 4, L1A, L1B);                                              \
        const float* Ep0 = EL[0][p];                                            \
        const float* Ep1 = EL[1][p];                                            \
        float4 ea0 = *reinterpret_cast<const float4*>(Ep0 + f0);                \
        float4 eb0 = *reinterpret_cast<const float4*>(Ep0 + f1);                \
        float4 ea1 = *reinterpret_cast<const float4*>(Ep1 + f0);                \
        float4 eb1 = *reinterpret_cast<const float4*>(Ep1 + f1);                \
        float x0, x1, x2, x3, y0, y1, y2, y3;                                   \
        MV32(ea0, eb0, x0, x1, x2, x3);                                         \
        MV32(ea1, eb1, y0, y1, y2, y3);                                         \
        RINGADD(x0, x1, x2, x3);                                                \
        RINGADD(y0, y1, y2, y3);                                                \
        float R0 = 1.0f, R1 = 1.0f;                                             \
        if ((C) == 3) {                   /* rebase: exact pow2, k=2 mod 4 */   \
            if (act0) {                                                         \
                float mx = fmaxf(ea0.z, eb0.z); RINGMAX(mx);                    \
                int e = (__float_as_int(mx) >> 23) & 0xFF;                      \
                R0 = __int_as_float((254 - e) << 23); Mint0 += e - 127;         \
            }                                                                   \
            if (act1) {                                                         \
                float mx = fmaxf(ea1.z, eb1.z); RINGMAX(mx);                    \
                int e = (__float_as_int(mx) >> 23) & 0xFF;                      \
                R1 = __int_as_float((254 - e) << 23); Mint1 += e - 127;         \
            }                                                                   \
        }                                                                       \
        if (o == 0) {                     /* all lanes hold sums post-ring */   \
            if (act0) *reinterpret_cast<float4*>(&EL[0][p ^ 1][wq]) =           \
                make_float4(x0 * Pa0.x * R0, x1 * Pa0.y * R0,                   \
                            x2 * Pb0.x * R0, x3 * Pb0.y * R0);                  \
            if (act1) *reinterpret_cast<float4*>(&EL[1][p ^ 1][wq]) =           \
                make_float4(y0 * Pa1.x * R1, y1 * Pa1.y * R1,                   \
                            y2 * Pb1.x * R1, y3 * Pb1.y * R1);                  \
        }                                                                       \
        Pa0 = (v2f){FEXP2(N0A.x * LOG2E), FEXP2(N0A.y * LOG2E)};                \
        Pb0 = (v2f){FEXP2(N0B.x * LOG2E), FEXP2(N0B.y * LOG2E)};                \
        Pa1 = (v2f){FEXP2(N1A.x * LOG2E), FEXP2(N1A.y * LOG2E)};                \
        Pb1 = (v2f){FEXP2(N1B.x * LOG2E), FEXP2(N1B.y * LOG2E)};                \
        STEP_BARRIER();                                                         \
    }

    for (int l4 = 0; l4 < len4; l4 += 4) {
        BODY(0, s0A0,s0B0, s1A0,s1B0,  s0A1,s0B1, s1A1,s1B1)
        BODY(1, s1A0,s1B0, s2A0,s2B0,  s1A1,s1B1, s2A1,s2B1)
        BODY(2, s2A0,s2B0, s3A0,s3B0,  s2A1,s2B1, s3A1,s3B1)
        BODY(3, s3A0,s3B0, s0A0,s0B0,  s3A1,s3B1, s0A1,s0B1)
    }
#undef BODY
#undef LOADP
    const int pf0 = len0 & 1, pf1 = len1 & 1;   // final E buffers

    // ---- score: emission + pairwise transitions, both batches ----
    float acc0 = 0.f, acc1 = 0.f;
    for (int l = tid; l < len0; l += 512) {
        int   tg = tb0[l];
        float tr = (l == 0) ? trans[tg * Tc + (Tc - 2)]
                            : trans[tg * Tc + tb0[l - 1]];
        acc0 += xb0[(size_t)l * Dc + tg] + tr;
    }
    for (int l = tid; l < len1; l += 512) {
        int   tg = tb1[l];
        float tr = (l == 0) ? trans[tg * Tc + (Tc - 2)]
                            : trans[tg * Tc + tb1[l - 1]];
        acc1 += xb1[(size_t)l * Dc + tg] + tr;
    }
#pragma unroll
    for (int off = 1; off < 64; off <<= 1) {
        acc0 += __shfl_xor(acc0, off, 64);
        acc1 += __shfl_xor(acc1, off, 64);
    }
    if (l6 == 0) { red[0][w] = acc0; red[1][w] = acc1; }

    // ---- partitions: wave 0 -> batch 0, wave 1 -> batch 1 ----
    if (w == 0) {
        int k0i = l6, k1i = 64 + l6;
        float p0 = FEXP2(trans[(Tc-1) * Tc + k0i] * LOG2E) * EL[0][pf0][Fmap(k0i)];
        float p1 = FEXP2(trans[(Tc-1) * Tc + k1i] * LOG2E) * EL[0][pf0][Fmap(k1i)];
        float ps = p0 + p1;
#pragma unroll
        for (int off = 1; off < 64; off <<= 1)
            ps += __shfl_xor(ps, off, 64);
        if (l6 == 0) red[0][8] = LN2 * ((float)Mint0 + FLOG2(ps));
    } else if (w == 1) {
        int k0i = l6, k1i = 64 + l6;
        float p0 = FEXP2(trans[(Tc-1) * Tc + k0i] * LOG2E) * EL[1][pf1][Fmap(k0i)];
        float p1 = FEXP2(trans[(Tc-1) * Tc + k1i] * LOG2E) * EL[1][pf1][Fmap(k1i)];
        float ps = p0 + p1;
#pragma unroll
        for (int off = 1; off < 64; off <<= 1)
            ps += __shfl_xor(ps, off, 64);
        if (l6 == 0) red[1][8] = LN2 * ((float)Mint1 + FLOG2(ps));
    }
    __syncthreads();

    if (tid == 0) {
        float sc0 = trans[(Tc-1) * Tc + tb0[len0 - 1]];
        float sc1 = trans[(Tc-1) * Tc + tb1[len1 - 1]];
#pragma unroll
        for (int i = 0; i < 8; ++i) { sc0 += red[0][i]; sc1 += red[1][i]; }
        out[bb]     = sc0 - red[0][8];
        out[bb + 1] = sc1 - red[1][8];
    }
}

extern "C" void kernel_launch(void* const* d_in, const int* in_sizes, int n_in,
                              void* d_out, int out_size, void* d_ws, size_t ws_size,
                              hipStream_t stream) {
    const float* x     = (const float*)d_in[0];
    const float* trans = (const float*)d_in[1];
    // d_in[2] = x_mask (redundant with x_len)
    const int*   x_len = (const int*)d_in[3];
    const int*   tag   = (const int*)d_in[4];
    float*       out   = (float*)d_out;

    crf_fwd_kernel<<<Bc / 2, 512, 0, stream>>>(x, trans, x_len, tag, out);
}

// Round 7
// 707.716 us; speedup vs baseline: 1.2214x; 1.2214x over previous
//
#include <hip/hip_runtime.h>

// CRF log-likelihood. B=256, L=1024, D=126, T=128. One block/batch, 128 thr
// = 2 WAVES (R10). Evidence R1/R3/R5: step time ~940-1050 cyc across 4x
// different LDS volume and 1.5x different VALU issue -> dominated by a
// ~450-500cyc barrier+drain+skew term at 8 waves. This probes the W=2
// quadrant: group of 8 lanes owns 8 outputs over k-slice of 16 (treg = 128
// VGPRs, under the 256 wall per R7 lesson), 4x ds_read_b128 broadcast
// (same-addr across the 8 groups = free), 128 FMA (8 indep chains),
// 3-stage DPP reduce, 7 cndmask to pick the lane's own output (replaces 7
// exp2+mul: each lane writes only E[tid], contiguous b32, 2-way = free).
// E quad-permuted pi(q)=q^(q>>2): reads conflict-free (distinct mod-8
// bank-quads over o for each read), writes 2-way. Logits: 1 coalesced
// dword/lane/step, prefetched 4 steps ahead in a static ring. One raw
// lgkmcnt(0)+s_barrier per step joining only 2 waves.

#define NEGV  (-10000.0f)
#define LOG2E 1.4426950408889634f
#define LN2   0.6931471805599453f

constexpr int Bc = 256, Lc = 1024, Dc = 126, Tc = 128;

#if __has_builtin(__builtin_amdgcn_exp2f)
#define FEXP2(x) __builtin_amdgcn_exp2f(x)
#else
#define FEXP2(x) exp2f(x)
#endif
#if __has_builtin(__builtin_amdgcn_logf)
#define FLOG2(x) __builtin_amdgcn_logf(x)
#else
#define FLOG2(x) log2f(x)
#endif

// DPP within the 8-lane k-group: quad xor1 (0xB1), quad xor2 (0x4E),
// row_half_mirror (0x141; i->7-i within each 8, valid 3rd stage once quads
// are uniform -- proven in R6/R9).
#if __has_builtin(__builtin_amdgcn_mov_dpp)
#define DPPF(x, ctrl) __int_as_float(__builtin_amdgcn_mov_dpp(__float_as_int(x), (ctrl), 0xF, 0xF, true))
#define QX1(x)  DPPF(x, 0xB1)
#define QX2(x)  DPPF(x, 0x4E)
#define HMIR(x) DPPF(x, 0x141)
#else
#define QX1(x)  __shfl_xor((x), 1, 64)
#define QX2(x)  __shfl_xor((x), 2, 64)
#define HMIR(x) __shfl_xor((x), 4, 64)
#endif

#define STEP_BARRIER() asm volatile("s_waitcnt lgkmcnt(0)\n\ts_barrier" ::: "memory")

// quad permutation: pi(q) = q ^ (q>>2) on [0,32), bijective.
__device__ __forceinline__ int PI(int q) { return q ^ (q >> 2); }
__device__ __forceinline__ int Fmap(int k) { return 4 * PI(k >> 2) + (k & 3); }

__global__ __launch_bounds__(128, 1) void crf_fwd_kernel(
    const float* __restrict__ x,      // [B, L, D]
    const float* __restrict__ trans,  // [T, T] row-major
    const int*   __restrict__ x_len,  // [B]
    const int*   __restrict__ tag,    // [B, L]
    float*       __restrict__ out)    // [B]
{
    __shared__ __align__(16) float E[2][Tc];   // rebased exp(alpha), dbuf, pi-permuted
    __shared__ float red[4];                   // epilogue reductions

    const int b   = blockIdx.x;
    const int tid = threadIdx.x;          // 0..127; own output j == tid
    const int w   = tid >> 6;             // wave 0..1
    const int l6  = tid & 63;
    const int o   = l6 & 7;               // lane-in-group: k in [16o, 16o+16)
    const int jb  = (tid >> 3) << 3;      // group's output base (8 outputs)
    const int len = x_len[b];             // block-uniform

    const float* xb = x   + (size_t)b * Lc * Dc;
    const int*   tb = tag + (size_t)b * Lc;

    const bool jOK = tid < Dc;            // tid 126,127 = START/STOP pad (P=0)

    // E read offsets (floats): quad 4o+c at permuted slot, c = 0..3.
    // Conflict-free: pi(4o+c) mod 8 distinct over o for every c.
    const int f0 = 4 * PI(4 * o + 0);
    const int f1 = 4 * PI(4 * o + 1);
    const int f2 = 4 * PI(4 * o + 2);
    const int f3 = 4 * PI(4 * o + 3);
    const int widx = Fmap(tid);           // own write slot (2-way banks = free)

    // ---- constant weights: treg[s][c] = exp(trans[jb+s, 16o+c]) : 128 VGPR ----
    float treg[8][16];
#pragma unroll
    for (int s = 0; s < 8; ++s) {
        const float4* tp = reinterpret_cast<const float4*>(trans + (jb + s) * Tc + (o << 4));
#pragma unroll
        for (int c4 = 0; c4 < 4; ++c4) {
            float4 t4 = tp[c4];
            treg[s][4*c4+0] = FEXP2(t4.x * LOG2E);
            treg[s][4*c4+1] = FEXP2(t4.y * LOG2E);
            treg[s][4*c4+2] = FEXP2(t4.z * LOG2E);
            treg[s][4*c4+3] = FEXP2(t4.w * LOG2E);
        }
    }

    // ---- init E = delta(START=126) ----
    E[0][widx] = (tid == Tc - 2) ? 1.0f : 0.0f;   // 128 threads cover all slots
    __syncthreads();

    // logit of row LS (clamped) for this lane's own output j = tid
#define LOADL(LS, DST) {                                        \
        int _s = (LS); if (_s > len - 1) _s = len - 1;          \
        DST = jOK ? xb[(size_t)_s * Dc + tid] : NEGV; }

    float P;                               // emission factor, current step
    { float l0; LOADL(0, l0); P = jOK ? FEXP2(l0 * LOG2E) : 0.0f; }
    float q0, q1, q2, q3;                  // 4-deep prefetch ring (static idx)
    LOADL(1, q1); LOADL(2, q2); LOADL(3, q3);
    q0 = q1;                               // placeholder; refilled at C=0

    int Mint = 0;                          // exact base-2 shift accumulator
    const int len4 = (len + 3) & ~3;

    // ---- forward recursion: one raw 2-wave barrier per step ----
#define BODY(C, QL, QN) {                                                       \
        const int  l   = l4 + (C);                                              \
        const bool act = l < len;         /* block-uniform tail guard */        \
        const int  p   = (C) & 1;                                               \
        LOADL(l + 4, QL);                 /* refill slot C, used at C+3 */      \
        const float* Ep = E[p];                                                 \
        float4 e0 = *reinterpret_cast<const float4*>(Ep + f0);                  \
        float4 e1 = *reinterpret_cast<const float4*>(Ep + f1);                  \
        float4 e2 = *reinterpret_cast<const float4*>(Ep + f2);                  \
        float4 e3 = *reinterpret_cast<const float4*>(Ep + f3);                  \
        float acc[8];                                                           \
        _Pragma("unroll")                                                       \
        for (int s = 0; s < 8; ++s) {     /* 8 indep 16-deep FMA chains */      \
            float a = treg[s][0] * e0.x;                                        \
            a = fmaf(treg[s][1],  e0.y, a);                                     \
            a = fmaf(treg[s][2],  e0.z, a);                                     \
            a = fmaf(treg[s][3],  e0.w, a);                                     \
            a = fmaf(treg[s][4],  e1.x, a);                                     \
            a = fmaf(treg[s][5],  e1.y, a);                                     \
            a = fmaf(treg[s][6],  e1.z, a);                                     \
            a = fmaf(treg[s][7],  e1.w, a);                                     \
            a = fmaf(treg[s][8],  e2.x, a);                                     \
            a = fmaf(treg[s][9],  e2.y, a);                                     \
            a = fmaf(treg[s][10], e2.z, a);                                     \
            a = fmaf(treg[s][11], e2.w, a);                                     \
            a = fmaf(treg[s][12], e3.x, a);                                     \
            a = fmaf(treg[s][13], e3.y, a);                                     \
            a = fmaf(treg[s][14], e3.z, a);                                     \
            a = fmaf(treg[s][15], e3.w, a);                                     \
            acc[s] = a;                                                         \
        }                                                                       \
        _Pragma("unroll")                                                       \
        for (int s = 0; s < 8; ++s) acc[s] += QX1(acc[s]);                      \
        _Pragma("unroll")                                                       \
        for (int s = 0; s < 8; ++s) acc[s] += QX2(acc[s]);                      \
        _Pragma("unroll")                                                       \
        for (int s = 0; s < 8; ++s) acc[s] += HMIR(acc[s]);                     \
        float R = 1.0f;                                                         \
        if ((C) == 3 && act) {            /* rebase: exact pow2, k=2 mod 4 */   \
            float mx = fmaxf(fmaxf(e0.z, e1.z), fmaxf(e2.z, e3.z));             \
            mx = fmaxf(mx, QX1(mx)); mx = fmaxf(mx, QX2(mx));                   \
            mx = fmaxf(mx, HMIR(mx));                                           \
            int ebq = (__float_as_int(mx) >> 23) & 0xFF;                        \
            R = __int_as_float((254 - ebq) << 23);                              \
            Mint += ebq - 127;                                                  \
        }                                                                       \
        /* select own output acc[o] via 3-level cndmask (o loop-invariant) */   \
        float sA = (o & 1) ? acc[1] : acc[0];                                   \
        float sB = (o & 1) ? acc[3] : acc[2];                                   \
        float sC = (o & 1) ? acc[5] : acc[4];                                   \
        float sD = (o & 1) ? acc[7] : acc[6];                                   \
        float sE = (o & 2) ? sB : sA;                                           \
        float sF = (o & 2) ? sD : sC;                                           \
        float sel = (o & 4) ? sF : sE;                                          \
        if (act) E[p ^ 1][widx] = sel * P * R;                                  \
        P = jOK ? FEXP2(QN * LOG2E) : 0.0f;                                     \
        STEP_BARRIER();                                                         \
    }

    for (int l4 = 0; l4 < len4; l4 += 4) {
        BODY(0, q0, q1)
        BODY(1, q1, q2)
        BODY(2, q2, q3)
        BODY(3, q3, q0)
    }
#undef BODY
#undef LOADL
    const int pf = len & 1;               // final E buffer

    // ---- score: emission + pairwise transitions (cooperative over l) ----
    float acc = 0.f;
    for (int l = tid; l < len; l += 128) {
        int   tg = tb[l];
        float tr = (l == 0) ? trans[tg * Tc + (Tc - 2)]
                            : trans[tg * Tc + tb[l - 1]];
        acc += xb[(size_t)l * Dc + tg] + tr;
    }
#pragma unroll
    for (int off = 1; off < 64; off <<= 1)
        acc += __shfl_xor(acc, off, 64);
    if (l6 == 0) red[w] = acc;

    // ---- partition = ln2 * (Mint + log2(sum_k exp(t_stop_k) * E_k)) ----
    if (w == 0) {
        int k0i = l6, k1i = 64 + l6;
        float p0 = FEXP2(trans[(Tc-1) * Tc + k0i] * LOG2E) * E[pf][Fmap(k0i)];
        float p1 = FEXP2(trans[(Tc-1) * Tc + k1i] * LOG2E) * E[pf][Fmap(k1i)];
        float ps = p0 + p1;
#pragma unroll
        for (int off = 1; off < 64; off <<= 1)
            ps += __shfl_xor(ps, off, 64);
        if (l6 == 0) red[2] = LN2 * ((float)Mint + FLOG2(ps));
    }
    __syncthreads();

    if (tid == 0) {
        float sc = red[0] + red[1] + trans[(Tc-1) * Tc + tb[len - 1]];
        out[b] = sc - red[2];
    }
}

extern "C" void kernel_launch(void* const* d_in, const int* in_sizes, int n_in,
                              void* d_out, int out_size, void* d_ws, size_t ws_size,
                              hipStream_t stream) {
    const float* x     = (const float*)d_in[0];
    const float* trans = (const float*)d_in[1];
    // d_in[2] = x_mask (redundant with x_len)
    const int*   x_len = (const int*)d_in[3];
    const int*   tag   = (const int*)d_in[4];
    float*       out   = (float*)d_out;

    crf_fwd_kernel<<<Bc, 128, 0, stream>>>(x, trans, x_len, tag, out);
}

// Round 8
// 482.557 us; speedup vs baseline: 1.7914x; 1.4666x over previous
//
#include <hip/hip_runtime.h>

// CRF log-likelihood. B=256, L=1024, D=126, T=128. One block/batch, 512 thr.
// R11 = R5's champion 8-wave structure (best measured: 966 cyc/step) on an
// ISSUE DIET. Evidence R1-R7: the step's ~550cyc stall core (write->drain->
// barrier->read->chain) needs 2 waves/SIMD to hide (W=2/W=4/1-wave all
// lost); the remaining lever is per-SIMD issue (~400 of 966 cyc). Cuts:
//  1. ONE logit load + ONE exp2 per thread (own output j=4jg+(o&3));
//     post-ring every lane holds all 4 sums -> 2-cndmask select + per-lane
//     b32 write replaces Pa/Pb (4 exp2 + 2 v2f loads + pad branch).
//  2. v_pk_fma_f32: 4 scalar chains -> 2 packed chains (24 vs 32 instr).
//  3. E rows padded 128->132: dbuf halves were bank-aligned (stride 128 =
//     0 mod 32) -> read-p vs write-p^1 collisions = R5's 9.2M conflicts.
// Everything else identical to R5: sig-permuted E, DPP row_ror ring over
// 16 lanes, rebase every 4th step (exact pow2), 4-deep static prefetch
// ring, raw lgkmcnt(0)+s_barrier.

typedef float v2f __attribute__((ext_vector_type(2)));

#define NEGV  (-10000.0f)
#define LOG2E 1.4426950408889634f
#define LN2   0.6931471805599453f

constexpr int Bc = 256, Lc = 1024, Dc = 126, Tc = 128;
constexpr int EP = Tc + 4;              // padded E row (bank de-alias)

#if __has_builtin(__builtin_amdgcn_exp2f)
#define FEXP2(x) __builtin_amdgcn_exp2f(x)
#else
#define FEXP2(x) exp2f(x)
#endif
#if __has_builtin(__builtin_amdgcn_logf)
#define FLOG2(x) __builtin_amdgcn_logf(x)
#else
#define FLOG2(x) log2f(x)
#endif

#if __has_builtin(__builtin_elementwise_fma)
#define PKFMA(a, b, c) __builtin_elementwise_fma((a), (b), (c))
#else
__device__ __forceinline__ v2f PKFMA(v2f a, v2f b, v2f c) {
    v2f r; r.x = fmaf(a.x, b.x, c.x); r.y = fmaf(a.y, b.y, c.y); return r;
}
#endif

// DPP row_ror:N within 16-lane rows (ring-reduce: after ror 1,2,4,8 every
// lane holds the full row total). Validated R5/R6.
#if __has_builtin(__builtin_amdgcn_mov_dpp)
#define DPPF(x, ctrl) __int_as_float(__builtin_amdgcn_mov_dpp(__float_as_int(x), (ctrl), 0xF, 0xF, true))
#define ROR1(x) DPPF(x, 0x121)
#define ROR2(x) DPPF(x, 0x122)
#define ROR4(x) DPPF(x, 0x124)
#define ROR8(x) DPPF(x, 0x128)
#else
#define ROR1(x) __shfl_xor((x), 1, 64)
#define ROR2(x) __shfl_xor((x), 2, 64)
#define ROR4(x) __shfl_xor((x), 4, 64)
#define ROR8(x) __shfl_xor((x), 8, 64)
#endif

#define STEP_BARRIER() asm volatile("s_waitcnt lgkmcnt(0)\n\ts_barrier" ::: "memory")

__device__ __forceinline__ int SIG(int q) { return q ^ (q >> 3); }   // bijective on [0,32)
__device__ __forceinline__ int Fmap(int k) { return 4 * SIG(k >> 2) + (k & 3); }

__global__ __launch_bounds__(512, 1) void crf_fwd_kernel(
    const float* __restrict__ x,      // [B, L, D]
    const float* __restrict__ trans,  // [T, T] row-major
    const int*   __restrict__ x_len,  // [B]
    const int*   __restrict__ tag,    // [B, L]
    float*       __restrict__ out)    // [B]
{
    __shared__ __align__(16) float E[2][EP];   // rebased exp(alpha), dbuf, sig-permuted
    __shared__ float red[12];                  // epilogue reductions

    const int b   = blockIdx.x;
    const int tid = threadIdx.x;
    const int w   = tid >> 6;             // wave 0..7
    const int l6  = tid & 63;
    const int o   = l6 & 15;              // k-octet: k in [8o, 8o+8)
    const int jg  = (w << 2) | (l6 >> 4); // j-group 0..31: j in [4jg, 4jg+4)
    const int len = x_len[b];             // block-uniform
    const int lenm1 = len - 1;

    const float* xb = x   + (size_t)b * Lc * Dc;
    const int*   tb = tag + (size_t)b * Lc;

    const int  f0 = 4 * SIG(2 * o);       // E read: k = 8o..8o+3
    const int  f1 = 4 * SIG(2 * o + 1);   //         k = 8o+4..8o+7
    const int  jown = 4 * jg + (o & 3);   // this thread's output state
    const bool jvalid = jown < Dc;        // j=126,127 are virtual NEG-pad
    const int  jr   = jvalid ? jown : 0;  // clamped load index
    const int  widx = 4 * SIG(jg) + (o & 3);  // own write slot (lanes o<4)

    // ---- constant weights, packed for pk_fma:
    // tP01[c] = {expT[4jg+0][8o+c], expT[4jg+1][8o+c]}, tP23 likewise ----
    v2f tP01[8], tP23[8];
    {
        const float4* t0p = reinterpret_cast<const float4*>(trans + (4*jg + 0) * Tc + 8*o);
        const float4* t1p = reinterpret_cast<const float4*>(trans + (4*jg + 1) * Tc + 8*o);
        const float4* t2p = reinterpret_cast<const float4*>(trans + (4*jg + 2) * Tc + 8*o);
        const float4* t3p = reinterpret_cast<const float4*>(trans + (4*jg + 3) * Tc + 8*o);
#pragma unroll
        for (int h = 0; h < 2; ++h) {
            float4 a = t0p[h], c = t1p[h], d = t2p[h], e = t3p[h];
            tP01[4*h+0] = (v2f){FEXP2(a.x*LOG2E), FEXP2(c.x*LOG2E)};
            tP01[4*h+1] = (v2f){FEXP2(a.y*LOG2E), FEXP2(c.y*LOG2E)};
            tP01[4*h+2] = (v2f){FEXP2(a.z*LOG2E), FEXP2(c.z*LOG2E)};
            tP01[4*h+3] = (v2f){FEXP2(a.w*LOG2E), FEXP2(c.w*LOG2E)};
            tP23[4*h+0] = (v2f){FEXP2(d.x*LOG2E), FEXP2(e.x*LOG2E)};
            tP23[4*h+1] = (v2f){FEXP2(d.y*LOG2E), FEXP2(e.y*LOG2E)};
            tP23[4*h+2] = (v2f){FEXP2(d.z*LOG2E), FEXP2(e.z*LOG2E)};
            tP23[4*h+3] = (v2f){FEXP2(d.w*LOG2E), FEXP2(e.w*LOG2E)};
        }
    }

    // ---- init E = delta(START=126) ----
    if (tid < Tc) E[0][Fmap(tid)] = (tid == Tc - 2) ? 1.0f : 0.0f;
    __syncthreads();

    // own-logit load for row LS (clamped), NEG for virtual states
#define LOADL(LS, DST) {                                        \
        int _s = (LS); if (_s > lenm1) _s = lenm1;              \
        float _v = xb[(size_t)_s * Dc + jr];                    \
        DST = jvalid ? _v : NEGV; }

    float P;                               // own emission factor, current step
    { float l0; LOADL(0, l0); P = FEXP2(l0 * LOG2E); }   // exp2(NEG*..) = 0
    float q0, q1, q2, q3;                  // 4-deep prefetch ring (static idx)
    LOADL(1, q1); LOADL(2, q2); LOADL(3, q3);
    q0 = q1;                               // placeholder; refilled at C=0

    int Mint = 0;                          // exact base-2 shift accumulator
    const int len4 = (len + 3) & ~3;

    // ---- forward recursion: one raw 8-wave barrier per step ----
#define BODY(C, QL, QN) {                                                       \
        const int  l   = l4 + (C);                                              \
        const bool act = l < len;         /* block-uniform tail guard */        \
        const int  p   = (C) & 1;                                               \
        LOADL(l + 4, QL);                 /* refill slot C, used at C+3 */      \
        const float* Ep = E[p];                                                 \
        float4 ea = *reinterpret_cast<const float4*>(Ep + f0);                  \
        float4 eb = *reinterpret_cast<const float4*>(Ep + f1);                  \
        v2f ee, acc01, acc23;                                                   \
        ee = (v2f){ea.x, ea.x}; acc01 = tP01[0] * ee; acc23 = tP23[0] * ee;     \
        ee = (v2f){ea.y, ea.y}; acc01 = PKFMA(tP01[1], ee, acc01);              \
                                acc23 = PKFMA(tP23[1], ee, acc23);              \
        ee = (v2f){ea.z, ea.z}; acc01 = PKFMA(tP01[2], ee, acc01);              \
                                acc23 = PKFMA(tP23[2], ee, acc23);              \
        ee = (v2f){ea.w, ea.w}; acc01 = PKFMA(tP01[3], ee, acc01);              \
                                acc23 = PKFMA(tP23[3], ee, acc23);              \
        ee = (v2f){eb.x, eb.x}; acc01 = PKFMA(tP01[4], ee, acc01);              \
                                acc23 = PKFMA(tP23[4], ee, acc23);              \
        ee = (v2f){eb.y, eb.y}; acc01 = PKFMA(tP01[5], ee, acc01);              \
                                acc23 = PKFMA(tP23[5], ee, acc23);              \
        ee = (v2f){eb.z, eb.z}; acc01 = PKFMA(tP01[6], ee, acc01);              \
                                acc23 = PKFMA(tP23[6], ee, acc23);              \
        ee = (v2f){eb.w, eb.w}; acc01 = PKFMA(tP01[7], ee, acc01);              \
                                acc23 = PKFMA(tP23[7], ee, acc23);              \
        float a0 = acc01.x, a1 = acc01.y, a2 = acc23.x, a3 = acc23.y;           \
        a0 += ROR1(a0); a1 += ROR1(a1); a2 += ROR1(a2); a3 += ROR1(a3);         \
        a0 += ROR2(a0); a1 += ROR2(a1); a2 += ROR2(a2); a3 += ROR2(a3);         \
        a0 += ROR4(a0); a1 += ROR4(a1); a2 += ROR4(a2); a3 += ROR4(a3);         \
        a0 += ROR8(a0); a1 += ROR8(a1); a2 += ROR8(a2); a3 += ROR8(a3);         \
        float R = 1.0f;                                                         \
        if ((C) == 3 && act) {            /* rebase: exact pow2, k=2 mod 4 */   \
            float mx = fmaxf(ea.z, eb.z);                                       \
            mx = fmaxf(mx, ROR1(mx)); mx = fmaxf(mx, ROR2(mx));                 \
            mx = fmaxf(mx, ROR4(mx)); mx = fmaxf(mx, ROR8(mx));                 \
            int ebq = (__float_as_int(mx) >> 23) & 0xFF;                        \
            R = __int_as_float((254 - ebq) << 23);                              \
            Mint += ebq - 127;                                                  \
        }                                                                       \
        /* every lane holds a0..a3 post-ring: pick own, write own b32 slot */   \
        float sA  = (o & 1) ? a1 : a0;                                          \
        float sB  = (o & 1) ? a3 : a2;                                          \
        float sel = (o & 2) ? sB : sA;                                          \
        if (act && o < 4) E[p ^ 1][widx] = sel * P * R;                         \
        P = FEXP2(QN * LOG2E);            /* own emission for step l+1 */       \
        STEP_BARRIER();                                                         \
    }

    for (int l4 = 0; l4 < len4; l4 += 4) {
        BODY(0, q0, q1)
        BODY(1, q1, q2)
        BODY(2, q2, q3)
        BODY(3, q3, q0)
    }
#undef BODY
#undef LOADL
    const int pf = len & 1;               // final E buffer

    // ---- score: emission + pairwise transitions (cooperative over l) ----
    float acc = 0.f;
    for (int l = tid; l < len; l += 512) {
        int   tg = tb[l];
        float tr = (l == 0) ? trans[tg * Tc + (Tc - 2)]
                            : trans[tg * Tc + tb[l - 1]];
        acc += xb[(size_t)l * Dc + tg] + tr;
    }
#pragma unroll
    for (int off = 1; off < 64; off <<= 1)
        acc += __shfl_xor(acc, off, 64);
    if (l6 == 0) red[w] = acc;

    // ---- partition = ln2 * (Mint + log2(sum_k exp(t_stop_k) * E_k)) ----
    if (w == 0) {
        int k0i = l6, k1i = 64 + l6;
        float p0 = FEXP2(trans[(Tc-1) * Tc + k0i] * LOG2E) * E[pf][Fmap(k0i)];
        float p1 = FEXP2(trans[(Tc-1) * Tc + k1i] * LOG2E) * E[pf][Fmap(k1i)];
        float ps = p0 + p1;
#pragma unroll
        for (int off = 1; off < 64; off <<= 1)
            ps += __shfl_xor(ps, off, 64);
        if (l6 == 0) red[8] = LN2 * ((float)Mint + FLOG2(ps));
    }
    __syncthreads();

    if (tid == 0) {
        float sc = trans[(Tc-1) * Tc + tb[len - 1]];   // STOP transition
#pragma unroll
        for (int i = 0; i < 8; ++i) sc += red[i];
        out[b] = sc - red[8];
    }
}

extern "C" void kernel_launch(void* const* d_in, const int* in_sizes, int n_in,
                              void* d_out, int out_size, void* d_ws, size_t ws_size,
                              hipStream_t stream) {
    const float* x     = (const float*)d_in[0];
    const float* trans = (const float*)d_in[1];
    // d_in[2] = x_mask (redundant with x_len)
    const int*   x_len = (const int*)d_in[3];
    const int*   tag   = (const int*)d_in[4];
    float*       out   = (float*)d_out;

    crf_fwd_kernel<<<Bc, 512, 0, stream>>>(x, trans, x_len, tag, out);
}